// Round 10
// baseline (386.556 us; speedup 1.0000x reference)
//
#include <hip/hip_runtime.h>
#include <hip/hip_fp16.h>

// GCN 2-layer inference, N=100000, E=1600000, F_IN=100, H=128, C=47.
// R13: plane-split gathers with R12 wave efficiency. R11 proved the XCD
// plane-residency mechanism (FETCH 108->61.5MB via plane=blockIdx&3 with
// XCD=blockIdx%8) but starved waves (1 node/wave = 1.3 iters -> 124us).
// R12 proved the wave structure (44.5us agg2) but pays full miss traffic.
// This round combines them: block = 4 waves x 4 nodes/wave (sequential,
// unrolled) x ONE plane; 16 nodes/block, grid 6250x4 (N divides exactly).
// Tables: xw8 -> 4 fp8 planes (32B rows, 3.2MB/plane), xw2 -> 4 fp16 planes
// (12 cols padded to 32B rows, 3.2MB/plane); both fit 4MB per-XCD L2.
// gemm1 plane epilogue verified in R11 (passed). CSR build + MFMA gemms
// unchanged from R12 (279.5us, absmax 0.0078 vs thr 0.0126).

typedef unsigned int uint32;
typedef float f32x2 __attribute__((ext_vector_type(2)));
typedef __fp16 fp16x2 __attribute__((ext_vector_type(2)));
typedef _Float16 h2v __attribute__((ext_vector_type(2)));
typedef _Float16 f16x8 __attribute__((ext_vector_type(8)));
typedef float f32x4 __attribute__((ext_vector_type(4)));

constexpr int N    = 100000;
constexpr int E    = 1600000;
constexpr int FIN  = 100;
constexpr int HD   = 128;
constexpr int C    = 47;
constexpr int C48  = 48;
constexpr int EN_CAP = E + 8 * N;    // padded edge-slot upper bound
constexpr int SCAN_CHUNK = 2048;     // 256 threads * 8
constexpr int NB_SCAN = (N + SCAN_CHUNK - 1) / SCAN_CHUNK;  // 49

// plane tables: 4 planes x (N+1) rows x 8 dwords (32B, line-pair aligned)
constexpr int PLANE = (N + 1) * 8;   // dwords per plane

// bucketed CSR build
constexpr int NPB   = 512;                          // nodes per bucket (dst>>9)
constexpr int NBUCK = (N + NPB - 1) / NPB;          // 196
constexpr int ABLK  = 400;                          // A-phase blocks
constexpr int EPB   = E / ABLK;                     // 4000 edges per A-block

// ---------- fp8 / fp16 helpers ----------

__device__ __forceinline__ uint32 pack_fp8x4(float x, float y, float z, float w) {
    int r = __builtin_amdgcn_cvt_pk_fp8_f32(x, y, 0, false);   // bytes 0,1
    r = __builtin_amdgcn_cvt_pk_fp8_f32(z, w, r, true);        // bytes 2,3
    return (uint32)r;
}

__device__ __forceinline__ void acc_fp8x4(uint32 v, float& a0, float& a1,
                                          float& a2, float& a3) {
    f32x2 lo = __builtin_amdgcn_cvt_pk_f32_fp8((int)v, false);
    f32x2 hi = __builtin_amdgcn_cvt_pk_f32_fp8((int)v, true);
    a0 += lo[0]; a1 += lo[1]; a2 += hi[0]; a3 += hi[1];
}

__device__ __forceinline__ uint32 pk16(float a, float b) {
    union { fp16x2 h; uint32 u; } x;
    x.h = __builtin_amdgcn_cvt_pkrtz(a, b);    // v_cvt_pkrtz_f16_f32
    return x.u;
}

// ---------- bucketed CSR build (no global atomics) ----------

__global__ __launch_bounds__(256) void bucket_hist(const int* __restrict__ dst,
                                                   int* __restrict__ blockhist) {
    __shared__ int h[NBUCK];
    int t = threadIdx.x, blk = blockIdx.x;
    for (int i = t; i < NBUCK; i += 256) h[i] = 0;
    __syncthreads();
    int base = blk * EPB;
    for (int i = t; i < EPB; i += 256)
        atomicAdd(&h[dst[base + i] >> 9], 1);
    __syncthreads();
    for (int i = t; i < NBUCK; i += 256) blockhist[i * ABLK + blk] = h[i];
}

__global__ __launch_bounds__(256) void scan_blocks(int* __restrict__ blockhist,
                                                   int* __restrict__ bcnt) {
    __shared__ int sm[512];
    int b = blockIdx.x, t = threadIdx.x;
    int v0 = (t       < ABLK) ? blockhist[b * ABLK + t] : 0;
    int v1 = (t + 256 < ABLK) ? blockhist[b * ABLK + t + 256] : 0;
    sm[t] = v0; sm[t + 256] = v1;
    __syncthreads();
    for (int off = 1; off < 512; off <<= 1) {
        int o0 = sm[t], o1 = sm[t + 256];
        int a0 = (t >= off) ? sm[t - off] : 0;
        int a1 = (t + 256 >= off) ? sm[t + 256 - off] : 0;
        __syncthreads();
        sm[t] = o0 + a0; sm[t + 256] = o1 + a1;
        __syncthreads();
    }
    if (t < ABLK)       blockhist[b * ABLK + t]       = sm[t] - v0;        // exclusive
    if (t + 256 < ABLK) blockhist[b * ABLK + t + 256] = sm[t + 256] - v1;
    if (t == 0) bcnt[b] = sm[ABLK - 1];
}

__global__ void scan_buckets(const int* __restrict__ bcnt, int* __restrict__ bbase) {
    if (threadIdx.x == 0) {
        int run = 0;
        for (int i = 0; i < NBUCK; ++i) { bbase[i] = run; run += bcnt[i]; }
        bbase[NBUCK] = run;   // == E
    }
}

__global__ __launch_bounds__(256) void bucket_scatter(const int* __restrict__ ei,
                                                      const int* __restrict__ blockhist,
                                                      const int* __restrict__ bbase,
                                                      uint32* __restrict__ pairs) {
    __shared__ int baseL[NBUCK];
    __shared__ int cur[NBUCK];
    int t = threadIdx.x, blk = blockIdx.x;
    for (int i = t; i < NBUCK; i += 256) {
        baseL[i] = bbase[i] + blockhist[i * ABLK + blk];
        cur[i] = 0;
    }
    __syncthreads();
    int base = blk * EPB;
    for (int i = t; i < EPB; i += 256) {
        int s = ei[base + i];
        int d = ei[E + base + i];
        int b = d >> 9;
        int off = atomicAdd(&cur[b], 1);
        pairs[baseL[b] + off] = (uint32)s | ((uint32)(d & (NPB - 1)) << 20);
    }
}

__global__ __launch_bounds__(256) void bucket_count(const uint32* __restrict__ pairs,
                                                    const int* __restrict__ bbase,
                                                    int* __restrict__ cnt) {
    __shared__ int c[NPB];
    int b = blockIdx.x, t = threadIdx.x;
    for (int i = t; i < NPB; i += 256) c[i] = 1;   // self loop
    __syncthreads();
    int beg = bbase[b], end = bbase[b + 1];
    for (int i = beg + t; i < end; i += 256)
        atomicAdd(&c[pairs[i] >> 20], 1);
    __syncthreads();
    int node0 = b * NPB;
    for (int i = t; i < NPB; i += 256) {
        int n = node0 + i;
        if (n < N) cnt[n] = c[i];
    }
}

__global__ __launch_bounds__(256) void bucket_place(const uint32* __restrict__ pairs,
                                                    const int* __restrict__ bbase,
                                                    const int* __restrict__ rowptr,
                                                    int* __restrict__ ep) {
    __shared__ int rowL[NPB];
    __shared__ int cur[NPB];
    int b = blockIdx.x, t = threadIdx.x;
    int node0 = b * NPB;
    for (int i = t; i < NPB; i += 256) {
        int n = node0 + i;
        rowL[i] = (n < N) ? rowptr[n] : 0;
        cur[i] = 1;   // slot 0 = self loop (written by scan_pass3)
    }
    __syncthreads();
    int beg = bbase[b], end = bbase[b + 1];
    for (int i = beg + t; i < end; i += 256) {
        uint32 p = pairs[i];
        int dl = p >> 20;
        int slot = atomicAdd(&cur[dl], 1);
        ep[rowL[dl] + slot] = (int)(p & 0xFFFFF);
    }
}

// ---------- global scan over node capacities ----------

__global__ void scan_pass1(const int* __restrict__ cnt, int* __restrict__ partials) {
    int t = threadIdx.x, b = blockIdx.x;
    int base = b * SCAN_CHUNK + t * 8;
    int s = 0;
#pragma unroll
    for (int i = 0; i < 8; ++i) {
        int idx = base + i;
        if (idx < N) s += (cnt[idx] + 7) & ~7;
    }
    __shared__ int sm[256];
    sm[t] = s;
    __syncthreads();
    for (int off = 128; off > 0; off >>= 1) {
        if (t < off) sm[t] += sm[t + off];
        __syncthreads();
    }
    if (t == 0) partials[b] = sm[0];
}

__global__ void scan_pass2(const int* __restrict__ partials, int* __restrict__ pscan,
                           int* __restrict__ rowptr) {
    if (threadIdx.x == 0) {
        int run = 0;
        for (int i = 0; i < NB_SCAN; ++i) { pscan[i] = run; run += partials[i]; }
        rowptr[N] = run;   // padded total, <= E + 8N
    }
}

__global__ void scan_pass3(const int* __restrict__ cnt, const int* __restrict__ pscan,
                           int* __restrict__ rowptr, float* __restrict__ dinv,
                           int* __restrict__ ep) {
    int t = threadIdx.x, b = blockIdx.x;
    int base = b * SCAN_CHUNK + t * 8;
    int v[8];
    int s = 0;
#pragma unroll
    for (int i = 0; i < 8; ++i) {
        int idx = base + i;
        v[i] = (idx < N) ? cnt[idx] : 0;
        s += (v[i] + 7) & ~7;
    }
    __shared__ int sm[256];
    sm[t] = s;
    __syncthreads();
    for (int off = 1; off < 256; off <<= 1) {
        int tv = (t >= off) ? sm[t - off] : 0;
        __syncthreads();
        sm[t] += tv;
        __syncthreads();
    }
    int excl = sm[t] - s + pscan[b];
#pragma unroll
    for (int i = 0; i < 8; ++i) {
        int idx = base + i;
        if (idx < N) {
            int cap = (v[i] + 7) & ~7;
            rowptr[idx] = excl;
            ep[excl] = idx;                  // self loop at slot 0
            dinv[idx] = rsqrtf((float)v[i]); // true degree (>=1)
            for (int k = v[i]; k < cap; ++k) ep[excl + k] = N;  // pads -> zero row
            excl += cap;
        }
    }
}

// ---------- GEMM1 (MFMA): xw8p planes fp8 = dinv[n]*(x @ W1) ----------
// Plane-split epilogue (verified in R11): dword D = nt*4+oct -> plane D>>3.

__global__ __launch_bounds__(256) void gemm1(const float* __restrict__ x,
                                             const float* __restrict__ W1,
                                             const float* __restrict__ dinv,
                                             uint32* __restrict__ xw8p) {
    __shared__ uint32 sA[8192];   // 32 KB, frag-linear: [(nt*4+ks)*256 + l*4 + d]
    int tx = threadIdx.x;

    for (int idx = tx; idx < 8192; idx += 256) {
        int slot = idx >> 8;               // nt*4 + ks
        int rem  = idx & 255;
        int l = rem >> 2, d = rem & 3;
        int nt = slot >> 2, ks = slot & 3;
        int n = nt * 16 + (l & 15);
        int k = ks * 32 + (l >> 4) * 8 + 2 * d;
        float va = (k < FIN)     ? W1[k * HD + n]       : 0.f;
        float vb = (k + 1 < FIN) ? W1[(k + 1) * HD + n] : 0.f;
        sA[idx] = pk16(va, vb);
    }
    __syncthreads();

    int l = tx & 63, w = tx >> 6;
    int m = l & 15, oct = l >> 4;
    size_t node0 = (size_t)blockIdx.x * 128 + (size_t)w * 32;
    size_t nA = node0 + m;          // node-tile 0
    size_t nB = node0 + 16 + m;     // node-tile 1

    f32x4 acc0[8], acc1[8];
#pragma unroll
    for (int nt = 0; nt < 8; ++nt) {
        acc0[nt] = (f32x4){0.f, 0.f, 0.f, 0.f};
        acc1[nt] = (f32x4){0.f, 0.f, 0.f, 0.f};
    }

#pragma unroll
    for (int ks = 0; ks < 4; ++ks) {
        int k0 = ks * 32 + oct * 8;
        float4 fa0 = make_float4(0.f, 0.f, 0.f, 0.f), fa1 = fa0;
        float4 fb0 = make_float4(0.f, 0.f, 0.f, 0.f), fb1 = fb0;
        if (nA < (size_t)N) {
            const float* xr = x + nA * FIN;
            if (k0 < FIN)     fa0 = *(const float4*)(xr + k0);
            if (k0 + 4 < FIN) fa1 = *(const float4*)(xr + k0 + 4);
        }
        if (nB < (size_t)N) {
            const float* xr = x + nB * FIN;
            if (k0 < FIN)     fb0 = *(const float4*)(xr + k0);
            if (k0 + 4 < FIN) fb1 = *(const float4*)(xr + k0 + 4);
        }
        union { uint4 u; f16x8 h; } b0, b1;
        b0.u = make_uint4(pk16(fa0.x, fa0.y), pk16(fa0.z, fa0.w),
                          pk16(fa1.x, fa1.y), pk16(fa1.z, fa1.w));
        b1.u = make_uint4(pk16(fb0.x, fb0.y), pk16(fb0.z, fb0.w),
                          pk16(fb1.x, fb1.y), pk16(fb1.z, fb1.w));
#pragma unroll
        for (int nt = 0; nt < 8; ++nt) {
            union { uint4 u; f16x8 h; } a;
            a.u = *(const uint4*)&sA[(nt * 4 + ks) * 256 + l * 4];
            acc0[nt] = __builtin_amdgcn_mfma_f32_16x16x32_f16(a.h, b0.h, acc0[nt], 0, 0, 0);
            acc1[nt] = __builtin_amdgcn_mfma_f32_16x16x32_f16(a.h, b1.h, acc1[nt], 0, 0, 0);
        }
    }

    if (nA <= (size_t)N) {
        float dv = (nA < (size_t)N) ? dinv[nA] : 0.f;
#pragma unroll
        for (int nt = 0; nt < 8; ++nt) {
            int D = nt * 4 + oct;
            f32x4 v = acc0[nt];
            uint32 p = (nA < (size_t)N)
                ? pack_fp8x4(v[0] * dv, v[1] * dv, v[2] * dv, v[3] * dv) : 0u;
            xw8p[(size_t)(D >> 3) * PLANE + nA * 8 + (D & 7)] = p;
        }
    }
    if (nB <= (size_t)N) {
        float dv = (nB < (size_t)N) ? dinv[nB] : 0.f;
#pragma unroll
        for (int nt = 0; nt < 8; ++nt) {
            int D = nt * 4 + oct;
            f32x4 v = acc1[nt];
            uint32 p = (nB < (size_t)N)
                ? pack_fp8x4(v[0] * dv, v[1] * dv, v[2] * dv, v[3] * dv) : 0u;
            xw8p[(size_t)(D >> 3) * PLANE + nB * 8 + (D & 7)] = p;
        }
    }
}

// ---------- agg1p: plane gather, 4 nodes/wave ----------
// block = 4 waves x 4 nodes x 1 plane (blockIdx&3); 16 nodes/block.
// lane = (es=lane>>3, d=lane&7): 8 edges x 8 dwords (32B fp8 row = 32 dims).

__global__ __launch_bounds__(256) void agg1p(const uint32* __restrict__ xw8p,
                                             const int* __restrict__ rowptr,
                                             const int* __restrict__ ep,
                                             const float* __restrict__ dinv,
                                             const float* __restrict__ b1,
                                             __half* __restrict__ h) {
    int plane = blockIdx.x & 3;
    int base = (blockIdx.x >> 2) * 16 + (threadIdx.x >> 6) * 4;  // N%16==0: all valid
    int lane = threadIdx.x & 63;
    int es = lane >> 3, d = lane & 7;
    const uint32* tab = xw8p + (size_t)plane * PLANE;
    int rp[5];
#pragma unroll
    for (int i = 0; i < 5; ++i) rp[i] = rowptr[base + i];
#pragma unroll
    for (int i = 0; i < 4; ++i) {
        int node = base + i;
        int beg = rp[i], end = rp[i + 1];   // cap, multiple of 8
        float a0 = 0.f, a1 = 0.f, a2 = 0.f, a3 = 0.f;
        int j = beg;
        for (; j + 16 <= end; j += 16) {
            int s0 = ep[j + es];
            int s1 = ep[j + 8 + es];
            uint32 v0 = tab[(size_t)s0 * 8 + d];
            uint32 v1 = tab[(size_t)s1 * 8 + d];
            acc_fp8x4(v0, a0, a1, a2, a3);
            acc_fp8x4(v1, a0, a1, a2, a3);
        }
        if (j < end) {   // 8 remaining
            int s0 = ep[j + es];
            uint32 v0 = tab[(size_t)s0 * 8 + d];
            acc_fp8x4(v0, a0, a1, a2, a3);
        }
        a0 += __shfl_xor(a0, 8); a0 += __shfl_xor(a0, 16); a0 += __shfl_xor(a0, 32);
        a1 += __shfl_xor(a1, 8); a1 += __shfl_xor(a1, 16); a1 += __shfl_xor(a1, 32);
        a2 += __shfl_xor(a2, 8); a2 += __shfl_xor(a2, 16); a2 += __shfl_xor(a2, 32);
        a3 += __shfl_xor(a3, 8); a3 += __shfl_xor(a3, 16); a3 += __shfl_xor(a3, 32);
        if (es == 0) {
            float dv = dinv[node];
            int dim0 = plane * 32 + d * 4;
            float4 bb = *(const float4*)&b1[dim0];
            float r0 = fmaxf(fmaf(dv, a0, bb.x), 0.f);
            float r1 = fmaxf(fmaf(dv, a1, bb.y), 0.f);
            float r2 = fmaxf(fmaf(dv, a2, bb.z), 0.f);
            float r3 = fmaxf(fmaf(dv, a3, bb.w), 0.f);
            union { __half2 h2[2]; uint2 u; } p;
            p.h2[0] = __floats2half2_rn(r0, r1);
            p.h2[1] = __floats2half2_rn(r2, r3);
            *(uint2*)&h[(size_t)node * HD + dim0] = p.u;
        }
    }
}

// ---------- GEMM2 (MFMA): xw2p planes fp16 = dinv[n]*(h @ W2) ----------
// A := W2^T frags; plane epilogue: col c -> plane c/12, slot c%12 (4-col
// groups never cross a 12-col plane since gcd(4,12)=4).

__global__ __launch_bounds__(256) void gemm2(const uint32* __restrict__ hh,
                                             const float* __restrict__ W2,
                                             const float* __restrict__ dinv,
                                             uint32* __restrict__ xw2p) {
    __shared__ uint32 sA[3072];   // 12 KB: [(nt*4+ks)*256 + l*4 + d]
    int tx = threadIdx.x;
    __half* xw2h = (__half*)xw2p;

    for (int idx = tx; idx < 3072; idx += 256) {
        int slot = idx >> 8;               // nt*4 + ks
        int rem  = idx & 255;
        int l = rem >> 2, d = rem & 3;
        int nt = slot >> 2, ks = slot & 3;
        int c = nt * 16 + (l & 15);
        int k = ks * 32 + (l >> 4) * 8 + 2 * d;
        float va = (c < C) ? W2[k * C + c]       : 0.f;
        float vb = (c < C) ? W2[(k + 1) * C + c] : 0.f;
        sA[idx] = pk16(va, vb);
    }
    __syncthreads();

    int l = tx & 63, w = tx >> 6;
    int m = l & 15, oct = l >> 4;
    size_t node0 = (size_t)blockIdx.x * 128 + (size_t)w * 32;
    size_t nA = node0 + m;
    size_t nB = node0 + 16 + m;

    f32x4 acc0[3], acc1[3];
#pragma unroll
    for (int nt = 0; nt < 3; ++nt) {
        acc0[nt] = (f32x4){0.f, 0.f, 0.f, 0.f};
        acc1[nt] = (f32x4){0.f, 0.f, 0.f, 0.f};
    }

#pragma unroll
    for (int ks = 0; ks < 4; ++ks) {
        union { uint4 u; f16x8 h; } b0, b1;
        b0.u = (nA < (size_t)N) ? *(const uint4*)&hh[nA * 64 + ks * 16 + oct * 4]
                                : make_uint4(0u, 0u, 0u, 0u);
        b1.u = (nB < (size_t)N) ? *(const uint4*)&hh[nB * 64 + ks * 16 + oct * 4]
                                : make_uint4(0u, 0u, 0u, 0u);
#pragma unroll
        for (int nt = 0; nt < 3; ++nt) {
            union { uint4 u; f16x8 h; } a;
            a.u = *(const uint4*)&sA[(nt * 4 + ks) * 256 + l * 4];
            acc0[nt] = __builtin_amdgcn_mfma_f32_16x16x32_f16(a.h, b0.h, acc0[nt], 0, 0, 0);
            acc1[nt] = __builtin_amdgcn_mfma_f32_16x16x32_f16(a.h, b1.h, acc1[nt], 0, 0, 0);
        }
    }

    if (nA <= (size_t)N) {
        float dv = (nA < (size_t)N) ? dinv[nA] : 0.f;
#pragma unroll
        for (int nt = 0; nt < 3; ++nt) {
            int c0 = nt * 16 + oct * 4;
            int plane = c0 / 12, slot0 = c0 - plane * 12;
            f32x4 v = acc0[nt];
            uint2 p = make_uint2(pk16(v[0] * dv, v[1] * dv),
                                 pk16(v[2] * dv, v[3] * dv));
            *(uint2*)&xw2h[(size_t)plane * PLANE * 2 + nA * 16 + slot0] = p;
        }
    }
    if (nB <= (size_t)N) {
        float dv = (nB < (size_t)N) ? dinv[nB] : 0.f;
#pragma unroll
        for (int nt = 0; nt < 3; ++nt) {
            int c0 = nt * 16 + oct * 4;
            int plane = c0 / 12, slot0 = c0 - plane * 12;
            f32x4 v = acc1[nt];
            uint2 p = make_uint2(pk16(v[0] * dv, v[1] * dv),
                                 pk16(v[2] * dv, v[3] * dv));
            *(uint2*)&xw2h[(size_t)plane * PLANE * 2 + nB * 16 + slot0] = p;
        }
    }
}

// ---------- agg2p: plane gather, 4 nodes/wave ----------
// rows 32B (12 cols fp16 in dwords 0-5, dwords 6-7 pad; pad lanes' sums
// are discarded by the d<6 write gate, never cross lanes of other d).

__global__ __launch_bounds__(256) void agg2p(const uint32* __restrict__ xw2p,
                                             const int* __restrict__ rowptr,
                                             const int* __restrict__ ep,
                                             const float* __restrict__ dinv,
                                             const float* __restrict__ b2,
                                             float* __restrict__ out) {
    int plane = blockIdx.x & 3;
    int base = (blockIdx.x >> 2) * 16 + (threadIdx.x >> 6) * 4;
    int lane = threadIdx.x & 63;
    int es = lane >> 3, d = lane & 7;
    const uint32* tab = xw2p + (size_t)plane * PLANE;
    int rp[5];
#pragma unroll
    for (int i = 0; i < 5; ++i) rp[i] = rowptr[base + i];
#pragma unroll
    for (int i = 0; i < 4; ++i) {
        int node = base + i;
        int beg = rp[i], end = rp[i + 1];
        float a0 = 0.f, a1 = 0.f;
        int j = beg;
        for (; j + 16 <= end; j += 16) {
            int s0 = ep[j + es];
            int s1 = ep[j + 8 + es];
            uint32 v0 = tab[(size_t)s0 * 8 + d];
            uint32 v1 = tab[(size_t)s1 * 8 + d];
            float2 f;
            f = __half22float2(*(const __half2*)&v0); a0 += f.x; a1 += f.y;
            f = __half22float2(*(const __half2*)&v1); a0 += f.x; a1 += f.y;
        }
        if (j < end) {
            int s0 = ep[j + es];
            uint32 v0 = tab[(size_t)s0 * 8 + d];
            float2 f = __half22float2(*(const __half2*)&v0); a0 += f.x; a1 += f.y;
        }
        a0 += __shfl_xor(a0, 8); a0 += __shfl_xor(a0, 16); a0 += __shfl_xor(a0, 32);
        a1 += __shfl_xor(a1, 8); a1 += __shfl_xor(a1, 16); a1 += __shfl_xor(a1, 32);
        if (es == 0 && d < 6) {
            float dv = dinv[node];
            int c = plane * 12 + d * 2;
            out[(size_t)node * C + c] = fmaf(dv, a0, b2[c]);
            if (c + 1 < C) out[(size_t)node * C + c + 1] = fmaf(dv, a1, b2[c + 1]);
        }
    }
}

extern "C" void kernel_launch(void* const* d_in, const int* in_sizes, int n_in,
                              void* d_out, int out_size, void* d_ws, size_t ws_size,
                              hipStream_t stream) {
    const float* x  = (const float*)d_in[0];
    const int*   ei = (const int*)d_in[1];
    const float* W1 = (const float*)d_in[2];
    const float* b1 = (const float*)d_in[3];
    const float* W2 = (const float*)d_in[4];
    const float* b2 = (const float*)d_in[5];
    float* out = (float*)d_out;

    size_t off = 0;
    auto alloc = [&](size_t bytes) {
        void* p = (char*)d_ws + off;
        off += (bytes + 255) & ~(size_t)255;
        return p;
    };
    int*    cnt       = (int*)alloc((size_t)N * 4);
    int*    rowptr    = (int*)alloc((size_t)(N + 1) * 4);
    int*    blockhist = (int*)alloc((size_t)NBUCK * ABLK * 4);
    int*    bcnt      = (int*)alloc((size_t)NBUCK * 4);
    int*    bbase     = (int*)alloc((size_t)(NBUCK + 1) * 4);
    uint32* pairs     = (uint32*)alloc((size_t)E * 4);
    int*    partials  = (int*)alloc(64 * 4);
    int*    pscan     = (int*)alloc(64 * 4);
    float*  dinv      = (float*)alloc((size_t)N * 4);
    int*    ep        = (int*)alloc((size_t)EN_CAP * 4);
    uint32* xw8p      = (uint32*)alloc((size_t)4 * PLANE * 4);   // fp8 planes
    __half* hh        = (__half*)alloc((size_t)N * HD * 2);
    uint32* xw2p      = (uint32*)alloc((size_t)4 * PLANE * 4);   // fp16 planes
    (void)ws_size;

    bucket_hist<<<ABLK, 256, 0, stream>>>(ei + E, blockhist);
    scan_blocks<<<NBUCK, 256, 0, stream>>>(blockhist, bcnt);
    scan_buckets<<<1, 64, 0, stream>>>(bcnt, bbase);
    bucket_scatter<<<ABLK, 256, 0, stream>>>(ei, blockhist, bbase, pairs);
    bucket_count<<<NBUCK, 256, 0, stream>>>(pairs, bbase, cnt);
    scan_pass1<<<NB_SCAN, 256, 0, stream>>>(cnt, partials);
    scan_pass2<<<1, 64, 0, stream>>>(partials, pscan, rowptr);
    scan_pass3<<<NB_SCAN, 256, 0, stream>>>(cnt, pscan, rowptr, dinv, ep);
    bucket_place<<<NBUCK, 256, 0, stream>>>(pairs, bbase, rowptr, ep);

    int ngrp16 = N / 16;   // 6250, exact
    gemm1<<<(N + 128) / 128, 256, 0, stream>>>(x, W1, dinv, xw8p);
    agg1p<<<ngrp16 * 4, 256, 0, stream>>>(xw8p, rowptr, ep, dinv, b1, hh);
    gemm2<<<(N + 128) / 128, 256, 0, stream>>>((const uint32*)hh, W2, dinv, xw2p);
    agg2p<<<ngrp16 * 4, 256, 0, stream>>>(xw2p, rowptr, ep, dinv, b2, out);
}

// Round 11
// 266.607 us; speedup vs baseline: 1.4499x; 1.4499x over previous
//
#include <hip/hip_runtime.h>
#include <hip/hip_fp16.h>

// GCN 2-layer inference, N=100000, E=1600000, F_IN=100, H=128, C=47.
// R14: fused atomic-allocation CSR build; aggs/gemms = R12 (279.5us base).
// R13 post-mortem: plane-split FETCH drop (108->61.5MB) confirmed twice but
// avg-degree-17 gives ~1.5 steps x 2 loads/lane -> latency-bound (102us);
// idea retired. This round: CSR segments need only be DISJOINT, not ordered
// -> atomic allocation removes both serial scan kernels and the separate
// histogram pass. 13 kernels -> 8:
//  init_small:       gbcur[b]=b*BCAP, galloc=0
//  bucket_scatter2:  LDS hist + per-bucket atomicAdd seg-alloc + scatter
//  bucket_countscan: LDS count + 512-scan + atomicAdd CSR base ->
//                    rowptr/rowend/dinv/selfloop/pads (rowend = explicit end)
//  bucket_place2:    LDS cursors -> ep
// aggs read rowend[node] instead of rowptr[node+1]. absmax expect 0.0078.

typedef unsigned int uint32;
typedef float f32x2 __attribute__((ext_vector_type(2)));
typedef __fp16 fp16x2 __attribute__((ext_vector_type(2)));
typedef _Float16 h2v __attribute__((ext_vector_type(2)));
typedef _Float16 f16x8 __attribute__((ext_vector_type(8)));
typedef float f32x4 __attribute__((ext_vector_type(4)));

constexpr int N    = 100000;
constexpr int E    = 1600000;
constexpr int FIN  = 100;
constexpr int HD   = 128;
constexpr int C    = 47;
constexpr int C48  = 48;
constexpr int EN_CAP = E + 8 * N;    // padded edge-slot upper bound

// bucketed CSR build
constexpr int NPB   = 512;                          // nodes per bucket (dst>>9)
constexpr int NBUCK = (N + NPB - 1) / NPB;          // 196
constexpr int ABLK  = 400;                          // scatter blocks
constexpr int EPB   = E / ABLK;                     // 4000 edges per block
constexpr int BCAP  = 16384;                        // bucket capacity (mean 8163 + 45 sigma)

// ---------- fp8 / fp16 helpers ----------

__device__ __forceinline__ uint32 pack_fp8x4(float x, float y, float z, float w) {
    int r = __builtin_amdgcn_cvt_pk_fp8_f32(x, y, 0, false);   // bytes 0,1
    r = __builtin_amdgcn_cvt_pk_fp8_f32(z, w, r, true);        // bytes 2,3
    return (uint32)r;
}

__device__ __forceinline__ void acc_fp8x4(uint32 v, float& a0, float& a1,
                                          float& a2, float& a3) {
    f32x2 lo = __builtin_amdgcn_cvt_pk_f32_fp8((int)v, false);
    f32x2 hi = __builtin_amdgcn_cvt_pk_f32_fp8((int)v, true);
    a0 += lo[0]; a1 += lo[1]; a2 += hi[0]; a3 += hi[1];
}

__device__ __forceinline__ uint32 pk16(float a, float b) {
    union { fp16x2 h; uint32 u; } x;
    x.h = __builtin_amdgcn_cvt_pkrtz(a, b);    // v_cvt_pkrtz_f16_f32
    return x.u;
}

// ---------- CSR build: 4 kernels, no serial passes ----------

__global__ void init_small(int* __restrict__ gbcur, int* __restrict__ galloc) {
    int t = threadIdx.x;
    for (int i = t; i < NBUCK; i += 256) gbcur[i] = i * BCAP;
    if (t == 0) *galloc = 0;
}

// LDS histogram + per-bucket segment alloc + scatter packed (dstLocal<<20|src)
__global__ __launch_bounds__(256) void bucket_scatter2(const int* __restrict__ ei,
                                                       int* __restrict__ gbcur,
                                                       uint32* __restrict__ pairs) {
    __shared__ int h[NBUCK];
    __shared__ int baseL[NBUCK];
    __shared__ int cur[NBUCK];
    int t = threadIdx.x, blk = blockIdx.x;
    for (int i = t; i < NBUCK; i += 256) h[i] = 0;
    __syncthreads();
    int base = blk * EPB;
    for (int i = t; i < EPB; i += 256)
        atomicAdd(&h[ei[E + base + i] >> 9], 1);
    __syncthreads();
    for (int i = t; i < NBUCK; i += 256) {
        baseL[i] = atomicAdd(&gbcur[i], h[i]);
        cur[i] = 0;
    }
    __syncthreads();
    for (int i = t; i < EPB; i += 256) {
        int s = ei[base + i];
        int d = ei[E + base + i];
        int b = d >> 9;
        int off = atomicAdd(&cur[b], 1);
        pairs[baseL[b] + off] = (uint32)s | ((uint32)(d & (NPB - 1)) << 20);
    }
}

// per-bucket degree count + 512-entry cap-scan + atomic CSR-base alloc ->
// rowptr/rowend/dinv + self-loop slot + pad slots (src=N -> zero row)
__global__ __launch_bounds__(256) void bucket_countscan(const uint32* __restrict__ pairs,
                                                        const int* __restrict__ gbcur,
                                                        int* __restrict__ galloc,
                                                        int* __restrict__ rowptr,
                                                        int* __restrict__ rowend,
                                                        float* __restrict__ dinv,
                                                        int* __restrict__ ep) {
    __shared__ int c[NPB];
    __shared__ int sm[NPB];
    __shared__ int sbase;
    int b = blockIdx.x, t = threadIdx.x;
    for (int i = t; i < NPB; i += 256) c[i] = 1;   // self loop
    __syncthreads();
    int pbase = b * BCAP;
    int blen = gbcur[b] - pbase;
    for (int i = t; i < blen; i += 256)
        atomicAdd(&c[pairs[pbase + i] >> 20], 1);
    __syncthreads();
    int node0 = b * NPB;
    int i0 = t, i1 = t + 256;
    int n0 = node0 + i0, n1 = node0 + i1;
    int deg0 = (n0 < N) ? c[i0] : 0;
    int deg1 = (n1 < N) ? c[i1] : 0;
    int cap0 = (deg0 + 7) & ~7;     // 0 stays 0 for invalid nodes
    int cap1 = (deg1 + 7) & ~7;
    sm[i0] = cap0; sm[i1] = cap1;
    __syncthreads();
    for (int off = 1; off < NPB; off <<= 1) {
        int o0 = sm[i0], o1 = sm[i1];
        int a0 = (i0 >= off) ? sm[i0 - off] : 0;
        int a1 = (i1 >= off) ? sm[i1 - off] : 0;
        __syncthreads();
        sm[i0] = o0 + a0; sm[i1] = o1 + a1;
        __syncthreads();
    }
    if (t == 0) sbase = atomicAdd(galloc, sm[NPB - 1]);
    __syncthreads();
    int gb = sbase;
    if (n0 < N) {
        int beg = gb + sm[i0] - cap0;
        rowptr[n0] = beg; rowend[n0] = beg + cap0;
        dinv[n0] = rsqrtf((float)deg0);
        ep[beg] = n0;                                  // self loop at slot 0
        for (int k = deg0; k < cap0; ++k) ep[beg + k] = N;  // pads -> zero row
    }
    if (n1 < N) {
        int beg = gb + sm[i1] - cap1;
        rowptr[n1] = beg; rowend[n1] = beg + cap1;
        dinv[n1] = rsqrtf((float)deg1);
        ep[beg] = n1;
        for (int k = deg1; k < cap1; ++k) ep[beg + k] = N;
    }
}

// per-bucket slot placement; ep writes stay inside the bucket's CSR ranges
__global__ __launch_bounds__(256) void bucket_place2(const uint32* __restrict__ pairs,
                                                     const int* __restrict__ gbcur,
                                                     const int* __restrict__ rowptr,
                                                     int* __restrict__ ep) {
    __shared__ int rowL[NPB];
    __shared__ int cur[NPB];
    int b = blockIdx.x, t = threadIdx.x;
    int node0 = b * NPB;
    for (int i = t; i < NPB; i += 256) {
        int n = node0 + i;
        rowL[i] = (n < N) ? rowptr[n] : 0;
        cur[i] = 1;   // slot 0 = self loop
    }
    __syncthreads();
    int pbase = b * BCAP;
    int blen = gbcur[b] - pbase;
    for (int i = t; i < blen; i += 256) {
        uint32 p = pairs[pbase + i];
        int dl = p >> 20;
        int slot = atomicAdd(&cur[dl], 1);
        ep[rowL[dl] + slot] = (int)(p & 0xFFFFF);
    }
}

// ---------- GEMM1 (MFMA): xw8[N+1,32 dwords] fp8 = dinv[n]*(x @ W1) ----------

__global__ __launch_bounds__(256) void gemm1(const float* __restrict__ x,
                                             const float* __restrict__ W1,
                                             const float* __restrict__ dinv,
                                             uint32* __restrict__ xw8) {
    __shared__ uint32 sA[8192];   // 32 KB, frag-linear: [(nt*4+ks)*256 + l*4 + d]
    int tx = threadIdx.x;

    for (int idx = tx; idx < 8192; idx += 256) {
        int slot = idx >> 8;               // nt*4 + ks
        int rem  = idx & 255;
        int l = rem >> 2, d = rem & 3;
        int nt = slot >> 2, ks = slot & 3;
        int n = nt * 16 + (l & 15);
        int k = ks * 32 + (l >> 4) * 8 + 2 * d;
        float va = (k < FIN)     ? W1[k * HD + n]       : 0.f;
        float vb = (k + 1 < FIN) ? W1[(k + 1) * HD + n] : 0.f;
        sA[idx] = pk16(va, vb);
    }
    __syncthreads();

    int l = tx & 63, w = tx >> 6;
    int m = l & 15, oct = l >> 4;
    size_t node0 = (size_t)blockIdx.x * 128 + (size_t)w * 32;
    size_t nA = node0 + m;          // node-tile 0
    size_t nB = node0 + 16 + m;     // node-tile 1

    f32x4 acc0[8], acc1[8];
#pragma unroll
    for (int nt = 0; nt < 8; ++nt) {
        acc0[nt] = (f32x4){0.f, 0.f, 0.f, 0.f};
        acc1[nt] = (f32x4){0.f, 0.f, 0.f, 0.f};
    }

#pragma unroll
    for (int ks = 0; ks < 4; ++ks) {
        int k0 = ks * 32 + oct * 8;
        float4 fa0 = make_float4(0.f, 0.f, 0.f, 0.f), fa1 = fa0;
        float4 fb0 = make_float4(0.f, 0.f, 0.f, 0.f), fb1 = fb0;
        if (nA < (size_t)N) {
            const float* xr = x + nA * FIN;
            if (k0 < FIN)     fa0 = *(const float4*)(xr + k0);
            if (k0 + 4 < FIN) fa1 = *(const float4*)(xr + k0 + 4);
        }
        if (nB < (size_t)N) {
            const float* xr = x + nB * FIN;
            if (k0 < FIN)     fb0 = *(const float4*)(xr + k0);
            if (k0 + 4 < FIN) fb1 = *(const float4*)(xr + k0 + 4);
        }
        union { uint4 u; f16x8 h; } b0, b1;
        b0.u = make_uint4(pk16(fa0.x, fa0.y), pk16(fa0.z, fa0.w),
                          pk16(fa1.x, fa1.y), pk16(fa1.z, fa1.w));
        b1.u = make_uint4(pk16(fb0.x, fb0.y), pk16(fb0.z, fb0.w),
                          pk16(fb1.x, fb1.y), pk16(fb1.z, fb1.w));
#pragma unroll
        for (int nt = 0; nt < 8; ++nt) {
            union { uint4 u; f16x8 h; } a;
            a.u = *(const uint4*)&sA[(nt * 4 + ks) * 256 + l * 4];
            acc0[nt] = __builtin_amdgcn_mfma_f32_16x16x32_f16(a.h, b0.h, acc0[nt], 0, 0, 0);
            acc1[nt] = __builtin_amdgcn_mfma_f32_16x16x32_f16(a.h, b1.h, acc1[nt], 0, 0, 0);
        }
    }

    if (nA <= (size_t)N) {
        float dv = (nA < (size_t)N) ? dinv[nA] : 0.f;
#pragma unroll
        for (int nt = 0; nt < 8; ++nt) {
            f32x4 v = acc0[nt];
            uint32 p = (nA < (size_t)N)
                ? pack_fp8x4(v[0] * dv, v[1] * dv, v[2] * dv, v[3] * dv) : 0u;
            xw8[nA * 32 + nt * 4 + oct] = p;
        }
    }
    if (nB <= (size_t)N) {
        float dv = (nB < (size_t)N) ? dinv[nB] : 0.f;
#pragma unroll
        for (int nt = 0; nt < 8; ++nt) {
            f32x4 v = acc1[nt];
            uint32 p = (nB < (size_t)N)
                ? pack_fp8x4(v[0] * dv, v[1] * dv, v[2] * dv, v[3] * dv) : 0u;
            xw8[nB * 32 + nt * 4 + oct] = p;
        }
    }
}

// ---------- agg1: h[n] (fp16) = relu(b1 + dinv[n] * sum_j xw8[src_j]) ----------
// R12 structure; 16-edge unroll (8 gather loads in flight), 8-edge tail.

__global__ __launch_bounds__(256) void agg1(const uint32* __restrict__ xw8,
                                            const int* __restrict__ rowptr,
                                            const int* __restrict__ rowend,
                                            const int* __restrict__ ep,
                                            const float* __restrict__ dinv,
                                            const float* __restrict__ b1,
                                            __half* __restrict__ h) {
    int node = blockIdx.x * 4 + (threadIdx.x >> 6);
    if (node >= N) return;
    int lane = threadIdx.x & 63;
    int hf = lane >> 5;      // which edge of the pair
    int q  = lane & 31;      // dword within 128B row -> dims q*4..q*4+3
    int beg = rowptr[node], end = rowend[node];   // cap, multiple of 8
    float a0 = 0.f, a1 = 0.f, a2 = 0.f, a3 = 0.f;
    int j = beg;
    for (; j + 16 <= end; j += 16) {
        int s0 = ep[j + hf];
        int s1 = ep[j + 2 + hf];
        int s2 = ep[j + 4 + hf];
        int s3 = ep[j + 6 + hf];
        int s4 = ep[j + 8 + hf];
        int s5 = ep[j + 10 + hf];
        int s6 = ep[j + 12 + hf];
        int s7 = ep[j + 14 + hf];
        uint32 v0 = xw8[(size_t)s0 * 32 + q];
        uint32 v1 = xw8[(size_t)s1 * 32 + q];
        uint32 v2 = xw8[(size_t)s2 * 32 + q];
        uint32 v3 = xw8[(size_t)s3 * 32 + q];
        uint32 v4 = xw8[(size_t)s4 * 32 + q];
        uint32 v5 = xw8[(size_t)s5 * 32 + q];
        uint32 v6 = xw8[(size_t)s6 * 32 + q];
        uint32 v7 = xw8[(size_t)s7 * 32 + q];
        acc_fp8x4(v0, a0, a1, a2, a3);
        acc_fp8x4(v1, a0, a1, a2, a3);
        acc_fp8x4(v2, a0, a1, a2, a3);
        acc_fp8x4(v3, a0, a1, a2, a3);
        acc_fp8x4(v4, a0, a1, a2, a3);
        acc_fp8x4(v5, a0, a1, a2, a3);
        acc_fp8x4(v6, a0, a1, a2, a3);
        acc_fp8x4(v7, a0, a1, a2, a3);
    }
    if (j < end) {   // 8 remaining
        int s0 = ep[j + hf];
        int s1 = ep[j + 2 + hf];
        int s2 = ep[j + 4 + hf];
        int s3 = ep[j + 6 + hf];
        uint32 v0 = xw8[(size_t)s0 * 32 + q];
        uint32 v1 = xw8[(size_t)s1 * 32 + q];
        uint32 v2 = xw8[(size_t)s2 * 32 + q];
        uint32 v3 = xw8[(size_t)s3 * 32 + q];
        acc_fp8x4(v0, a0, a1, a2, a3);
        acc_fp8x4(v1, a0, a1, a2, a3);
        acc_fp8x4(v2, a0, a1, a2, a3);
        acc_fp8x4(v3, a0, a1, a2, a3);
    }
    a0 += __shfl_xor(a0, 32);
    a1 += __shfl_xor(a1, 32);
    a2 += __shfl_xor(a2, 32);
    a3 += __shfl_xor(a3, 32);
    if (hf == 0) {
        float dv = dinv[node];
        float4 bb = *(const float4*)&b1[q * 4];
        float r0 = fmaxf(fmaf(dv, a0, bb.x), 0.f);
        float r1 = fmaxf(fmaf(dv, a1, bb.y), 0.f);
        float r2 = fmaxf(fmaf(dv, a2, bb.z), 0.f);
        float r3 = fmaxf(fmaf(dv, a3, bb.w), 0.f);
        union { __half2 h2[2]; uint2 u; } p;
        p.h2[0] = __floats2half2_rn(r0, r1);
        p.h2[1] = __floats2half2_rn(r2, r3);
        *(uint2*)&h[(size_t)node * HD + q * 4] = p.u;
    }
}

// ---------- GEMM2 (MFMA): xw2h[N+1,48] fp16 = dinv[n]*(h @ W2), col47=0 ----------

__global__ __launch_bounds__(256) void gemm2(const uint32* __restrict__ hh,
                                             const float* __restrict__ W2,
                                             const float* __restrict__ dinv,
                                             __half* __restrict__ xw2h) {
    __shared__ uint32 sA[3072];   // 12 KB: [(nt*4+ks)*256 + l*4 + d]
    int tx = threadIdx.x;

    for (int idx = tx; idx < 3072; idx += 256) {
        int slot = idx >> 8;               // nt*4 + ks
        int rem  = idx & 255;
        int l = rem >> 2, d = rem & 3;
        int nt = slot >> 2, ks = slot & 3;
        int c = nt * 16 + (l & 15);
        int k = ks * 32 + (l >> 4) * 8 + 2 * d;
        float va = (c < C) ? W2[k * C + c]       : 0.f;
        float vb = (c < C) ? W2[(k + 1) * C + c] : 0.f;
        sA[idx] = pk16(va, vb);
    }
    __syncthreads();

    int l = tx & 63, w = tx >> 6;
    int m = l & 15, oct = l >> 4;
    size_t node0 = (size_t)blockIdx.x * 128 + (size_t)w * 32;
    size_t nA = node0 + m;
    size_t nB = node0 + 16 + m;

    f32x4 acc0[3], acc1[3];
#pragma unroll
    for (int nt = 0; nt < 3; ++nt) {
        acc0[nt] = (f32x4){0.f, 0.f, 0.f, 0.f};
        acc1[nt] = (f32x4){0.f, 0.f, 0.f, 0.f};
    }

#pragma unroll
    for (int ks = 0; ks < 4; ++ks) {
        union { uint4 u; f16x8 h; } b0, b1;
        b0.u = (nA < (size_t)N) ? *(const uint4*)&hh[nA * 64 + ks * 16 + oct * 4]
                                : make_uint4(0u, 0u, 0u, 0u);
        b1.u = (nB < (size_t)N) ? *(const uint4*)&hh[nB * 64 + ks * 16 + oct * 4]
                                : make_uint4(0u, 0u, 0u, 0u);
#pragma unroll
        for (int nt = 0; nt < 3; ++nt) {
            union { uint4 u; f16x8 h; } a;
            a.u = *(const uint4*)&sA[(nt * 4 + ks) * 256 + l * 4];
            acc0[nt] = __builtin_amdgcn_mfma_f32_16x16x32_f16(a.h, b0.h, acc0[nt], 0, 0, 0);
            acc1[nt] = __builtin_amdgcn_mfma_f32_16x16x32_f16(a.h, b1.h, acc1[nt], 0, 0, 0);
        }
    }

    if (nA <= (size_t)N) {
        float dv = (nA < (size_t)N) ? dinv[nA] : 0.f;
#pragma unroll
        for (int nt = 0; nt < 3; ++nt) {
            int c0 = nt * 16 + oct * 4;
            f32x4 v = acc0[nt];
            uint2 p = make_uint2(pk16(v[0] * dv, v[1] * dv),
                                 pk16(v[2] * dv, v[3] * dv));
            *(uint2*)&xw2h[nA * C48 + c0] = p;   // col47: A-pad=0 -> writes 0
        }
    }
    if (nB <= (size_t)N) {
        float dv = (nB < (size_t)N) ? dinv[nB] : 0.f;
#pragma unroll
        for (int nt = 0; nt < 3; ++nt) {
            int c0 = nt * 16 + oct * 4;
            f32x4 v = acc1[nt];
            uint2 p = make_uint2(pk16(v[0] * dv, v[1] * dv),
                                 pk16(v[2] * dv, v[3] * dv));
            *(uint2*)&xw2h[nB * C48 + c0] = p;
        }
    }
}

// ---------- agg2: out[n] = b2 + dinv[n] * sum_j xw2[src_j] ----------
// R12 structure; 16-edge unroll, 8-edge tail.

__global__ __launch_bounds__(256) void agg2(const uint32* __restrict__ xw2d,
                                            const int* __restrict__ rowptr,
                                            const int* __restrict__ rowend,
                                            const int* __restrict__ ep,
                                            const float* __restrict__ dinv,
                                            const float* __restrict__ b2,
                                            float* __restrict__ out) {
    int node = blockIdx.x * 4 + (threadIdx.x >> 6);
    if (node >= N) return;
    int lane = threadIdx.x & 63;
    int hf = lane >> 5;      // which edge of the pair
    int q  = lane & 31;      // dword within row (only q<24 valid)
    bool act = q < 24;
    int beg = rowptr[node], end = rowend[node];   // cap, multiple of 8
    float a0 = 0.f, a1 = 0.f;
    int j = beg;
    for (; j + 16 <= end; j += 16) {
        int s0 = ep[j + hf];
        int s1 = ep[j + 2 + hf];
        int s2 = ep[j + 4 + hf];
        int s3 = ep[j + 6 + hf];
        int s4 = ep[j + 8 + hf];
        int s5 = ep[j + 10 + hf];
        int s6 = ep[j + 12 + hf];
        int s7 = ep[j + 14 + hf];
        if (act) {
            uint32 v0 = xw2d[(size_t)s0 * 24 + q];
            uint32 v1 = xw2d[(size_t)s1 * 24 + q];
            uint32 v2 = xw2d[(size_t)s2 * 24 + q];
            uint32 v3 = xw2d[(size_t)s3 * 24 + q];
            uint32 v4 = xw2d[(size_t)s4 * 24 + q];
            uint32 v5 = xw2d[(size_t)s5 * 24 + q];
            uint32 v6 = xw2d[(size_t)s6 * 24 + q];
            uint32 v7 = xw2d[(size_t)s7 * 24 + q];
            float2 f;
            f = __half22float2(*(const __half2*)&v0); a0 += f.x; a1 += f.y;
            f = __half22float2(*(const __half2*)&v1); a0 += f.x; a1 += f.y;
            f = __half22float2(*(const __half2*)&v2); a0 += f.x; a1 += f.y;
            f = __half22float2(*(const __half2*)&v3); a0 += f.x; a1 += f.y;
            f = __half22float2(*(const __half2*)&v4); a0 += f.x; a1 += f.y;
            f = __half22float2(*(const __half2*)&v5); a0 += f.x; a1 += f.y;
            f = __half22float2(*(const __half2*)&v6); a0 += f.x; a1 += f.y;
            f = __half22float2(*(const __half2*)&v7); a0 += f.x; a1 += f.y;
        }
    }
    if (j < end) {   // 8 remaining
        int s0 = ep[j + hf];
        int s1 = ep[j + 2 + hf];
        int s2 = ep[j + 4 + hf];
        int s3 = ep[j + 6 + hf];
        if (act) {
            uint32 v0 = xw2d[(size_t)s0 * 24 + q];
            uint32 v1 = xw2d[(size_t)s1 * 24 + q];
            uint32 v2 = xw2d[(size_t)s2 * 24 + q];
            uint32 v3 = xw2d[(size_t)s3 * 24 + q];
            float2 f;
            f = __half22float2(*(const __half2*)&v0); a0 += f.x; a1 += f.y;
            f = __half22float2(*(const __half2*)&v1); a0 += f.x; a1 += f.y;
            f = __half22float2(*(const __half2*)&v2); a0 += f.x; a1 += f.y;
            f = __half22float2(*(const __half2*)&v3); a0 += f.x; a1 += f.y;
        }
    }
    a0 += __shfl_xor(a0, 32);
    a1 += __shfl_xor(a1, 32);
    if (hf == 0 && act) {
        float dv = dinv[node];
        int c = q * 2;
        out[(size_t)node * C + c] = fmaf(dv, a0, b2[c]);
        if (c + 1 < C) out[(size_t)node * C + c + 1] = fmaf(dv, a1, b2[c + 1]);
    }
}

extern "C" void kernel_launch(void* const* d_in, const int* in_sizes, int n_in,
                              void* d_out, int out_size, void* d_ws, size_t ws_size,
                              hipStream_t stream) {
    const float* x  = (const float*)d_in[0];
    const int*   ei = (const int*)d_in[1];
    const float* W1 = (const float*)d_in[2];
    const float* b1 = (const float*)d_in[3];
    const float* W2 = (const float*)d_in[4];
    const float* b2 = (const float*)d_in[5];
    float* out = (float*)d_out;

    size_t off = 0;
    auto alloc = [&](size_t bytes) {
        void* p = (char*)d_ws + off;
        off += (bytes + 255) & ~(size_t)255;
        return p;
    };
    int*    gbcur   = (int*)alloc((size_t)NBUCK * 4);
    int*    galloc  = (int*)alloc(256);
    uint32* pairs   = (uint32*)alloc((size_t)NBUCK * BCAP * 4);   // 12.8 MB
    int*    rowptr  = (int*)alloc((size_t)N * 4);
    int*    rowend  = (int*)alloc((size_t)N * 4);
    float*  dinv    = (float*)alloc((size_t)N * 4);
    int*    ep      = (int*)alloc((size_t)EN_CAP * 4);
    uint32* xw8     = (uint32*)alloc((size_t)(N + 1) * 32 * 4);   // fp8 [N+1][128]
    __half* hh      = (__half*)alloc((size_t)N * HD * 2);
    __half* xw2h    = (__half*)alloc((size_t)(N + 1) * C48 * 2);  // fp16 [N+1][48]
    (void)ws_size;

    init_small<<<1, 256, 0, stream>>>(gbcur, galloc);
    bucket_scatter2<<<ABLK, 256, 0, stream>>>(ei, gbcur, pairs);
    bucket_countscan<<<NBUCK, 256, 0, stream>>>(pairs, gbcur, galloc,
                                                rowptr, rowend, dinv, ep);
    bucket_place2<<<NBUCK, 256, 0, stream>>>(pairs, gbcur, rowptr, ep);

    gemm1<<<(N + 128) / 128, 256, 0, stream>>>(x, W1, dinv, xw8);   // covers node N
    agg1<<<(N + 3) / 4, 256, 0, stream>>>(xw8, rowptr, rowend, ep, dinv, b1, hh);
    gemm2<<<(N + 128) / 128, 256, 0, stream>>>((const uint32*)hh, W2, dinv, xw2h);
    agg2<<<(N + 3) / 4, 256, 0, stream>>>((const uint32*)xw2h, rowptr, rowend, ep, dinv, b2, out);
}